// Round 1
// baseline (7554.115 us; speedup 1.0000x reference)
//
#include <hip/hip_runtime.h>
#include <hip/hip_bf16.h>

// Problem constants (from reference setup_inputs)
#define BSZ   2
#define TSEQ  2048
#define CDIM  4096
#define NH    32
#define NKV   8
#define GQ    4          // NH / NKV
#define DH    128
#define BT    (BSZ * TSEQ)   // 4096 rows

// ---------------- fp32 SGEMM with optional fused RoPE epilogue ----------------
// C[M x N] = A[M x K] @ B[K x N], M=BT, K=CDIM. 128x128 block tile, 8x8 micro.
#define BLK 128
#define KT  16

__global__ __launch_bounds__(256) void gemm_rope(
    const float* __restrict__ A, const float* __restrict__ B, float* __restrict__ C,
    int N, int K,
    const float* __restrict__ cosb, const float* __restrict__ sinb, int rope) {
  __shared__ float As[KT][BLK + 4];   // transposed A tile: As[k][m]
  __shared__ float Bs[KT][BLK + 4];   // Bs[k][n]
  const int tid = threadIdx.x;
  const int tx = tid & 15;            // 16 cols of threads
  const int ty = tid >> 4;            // 16 rows of threads
  const int row0 = blockIdx.y * BLK;
  const int col0 = blockIdx.x * BLK;

  float acc[8][8];
  #pragma unroll
  for (int i = 0; i < 8; ++i)
    #pragma unroll
    for (int j = 0; j < 8; ++j) acc[i][j] = 0.f;

  for (int k0 = 0; k0 < K; k0 += KT) {
    // A tile: 128 rows x 16 k -> transposed into As
    {
      int idx = tid;
      #pragma unroll
      for (int it = 0; it < 2; ++it, idx += 256) {
        int r  = idx >> 2;   // 0..127
        int c4 = idx & 3;    // 0..3 (x4 floats)
        const float4 va = *(const float4*)&A[(size_t)(row0 + r) * K + k0 + c4 * 4];
        As[c4*4+0][r] = va.x; As[c4*4+1][r] = va.y;
        As[c4*4+2][r] = va.z; As[c4*4+3][r] = va.w;
      }
    }
    // B tile: 16 k x 128 cols
    {
      int idx = tid;
      #pragma unroll
      for (int it = 0; it < 2; ++it, idx += 256) {
        int r  = idx >> 5;   // 0..15
        int c4 = idx & 31;   // 0..31
        const float4 vb = *(const float4*)&B[(size_t)(k0 + r) * N + col0 + c4 * 4];
        *(float4*)&Bs[r][c4 * 4] = vb;
      }
    }
    __syncthreads();
    #pragma unroll
    for (int kk = 0; kk < KT; ++kk) {
      float a[8], b[8];
      *(float4*)&a[0] = *(const float4*)&As[kk][ty * 8];
      *(float4*)&a[4] = *(const float4*)&As[kk][ty * 8 + 4];
      *(float4*)&b[0] = *(const float4*)&Bs[kk][tx * 8];
      *(float4*)&b[4] = *(const float4*)&Bs[kk][tx * 8 + 4];
      #pragma unroll
      for (int i = 0; i < 8; ++i)
        #pragma unroll
        for (int j = 0; j < 8; ++j)
          acc[i][j] += a[i] * b[j];
    }
    __syncthreads();
  }

  const int cbase = col0 + tx * 8;
  if (rope) {
    // interleaved RoPE: pairs (2i,2i+1) within each head's 128-wide slice.
    // cos/sin are stored repeated x2, so c for pair p is cosb[t*128 + 2i].
    #pragma unroll
    for (int i = 0; i < 8; ++i) {
      int r = row0 + ty * 8 + i;
      int t = r & (TSEQ - 1);          // row -> sequence position
      const float* cr = &cosb[(size_t)t * DH];
      const float* sr = &sinb[(size_t)t * DH];
      float out[8];
      #pragma unroll
      for (int j = 0; j < 8; j += 2) {
        int cp = (cbase + j) & (DH - 1);   // position within head (even)
        float c = cr[cp], s = sr[cp];
        float x1 = acc[i][j], x2 = acc[i][j + 1];
        out[j]     = x1 * c - x2 * s;
        out[j + 1] = x1 * s + x2 * c;
      }
      *(float4*)&C[(size_t)r * N + cbase]     = *(float4*)&out[0];
      *(float4*)&C[(size_t)r * N + cbase + 4] = *(float4*)&out[4];
    }
  } else {
    #pragma unroll
    for (int i = 0; i < 8; ++i) {
      int r = row0 + ty * 8 + i;
      *(float4*)&C[(size_t)r * N + cbase]     = *(float4*)&acc[i][0];
      *(float4*)&C[(size_t)r * N + cbase + 4] = *(float4*)&acc[i][4];
    }
  }
}

// ---------------- flash attention, fp32, online softmax ----------------
// grid: (TSEQ/BM, NH, BSZ). block 256 = 32 rows x 8 col-groups.
#define BM 32
#define BN 32

__global__ __launch_bounds__(256) void flash_kernel(
    const float* __restrict__ q,   // (BT, 4096) col = h*128+d
    const float* __restrict__ k,   // (BT, 1024) col = kvh*128+d
    const float* __restrict__ v,   // (BT, 1024)
    float* __restrict__ o,         // (BT, 4096)
    const int* __restrict__ causal_p) {
  __shared__ float Qs[DH][BM + 1];   // transposed: Qs[d][r], pad -> conflict-free
  __shared__ float Ks[DH][BN + 1];
  __shared__ float Vs[BN][DH];       // natural: broadcast reads
  __shared__ float Ps[BM][BN + 1];
  __shared__ float red[BM][8];
  __shared__ float m_sh[BM], l_sh[BM], alpha_sh[BM];

  const int tid = threadIdx.x;
  const int row = tid & 31;          // q row within tile
  const int cg  = tid >> 5;          // 0..7 col group
  const int mtile = blockIdx.x;
  const int h  = blockIdx.y;
  const int b  = blockIdx.z;
  const int kvh = h / GQ;
  const int m0 = mtile * BM;
  const bool causal = (*causal_p != 0);
  const float NEG_INF = -__builtin_inff();

  // load Q tile transposed
  for (int idx = tid; idx < BM * (DH / 4); idx += 256) {
    int r  = idx / (DH / 4);
    int c4 = idx % (DH / 4);
    const float4 vq = *(const float4*)&q[(size_t)(b * TSEQ + m0 + r) * CDIM + h * DH + c4 * 4];
    Qs[c4*4+0][r] = vq.x; Qs[c4*4+1][r] = vq.y;
    Qs[c4*4+2][r] = vq.z; Qs[c4*4+3][r] = vq.w;
  }
  if (tid < BM) { m_sh[tid] = NEG_INF; l_sh[tid] = 0.f; }

  float O[16];
  #pragma unroll
  for (int i = 0; i < 16; ++i) O[i] = 0.f;

  const int ntiles = causal ? (mtile + 1) : (TSEQ / BN);
  const float scale = 0.08838834764831845f;  // 1/sqrt(128)
  const int jl0 = cg * 4;
  const int d0  = cg * 16;

  for (int tile = 0; tile < ntiles; ++tile) {
    const int j0 = tile * BN;
    __syncthreads();   // protect Ks/Vs/Ps/red from previous iteration readers
    for (int idx = tid; idx < BN * (DH / 4); idx += 256) {
      int r  = idx / (DH / 4);
      int c4 = idx % (DH / 4);
      size_t goff = (size_t)(b * TSEQ + j0 + r) * (NKV * DH) + kvh * DH + c4 * 4;
      const float4 vk = *(const float4*)&k[goff];
      Ks[c4*4+0][r] = vk.x; Ks[c4*4+1][r] = vk.y;
      Ks[c4*4+2][r] = vk.z; Ks[c4*4+3][r] = vk.w;
      *(float4*)&Vs[r][c4 * 4] = *(const float4*)&v[goff];
    }
    __syncthreads();

    // scores: each thread 4 columns
    float s0 = 0.f, s1 = 0.f, s2 = 0.f, s3 = 0.f;
    #pragma unroll 4
    for (int d = 0; d < DH; ++d) {
      float qv = Qs[d][row];
      s0 += qv * Ks[d][jl0 + 0];
      s1 += qv * Ks[d][jl0 + 1];
      s2 += qv * Ks[d][jl0 + 2];
      s3 += qv * Ks[d][jl0 + 3];
    }
    float sc[4] = {s0 * scale, s1 * scale, s2 * scale, s3 * scale};
    const int t_glob = m0 + row;
    if (causal) {
      #pragma unroll
      for (int c = 0; c < 4; ++c)
        if (j0 + jl0 + c > t_glob) sc[c] = NEG_INF;
    }
    float pmax = fmaxf(fmaxf(sc[0], sc[1]), fmaxf(sc[2], sc[3]));
    red[row][cg] = pmax;
    __syncthreads();
    if (tid < BM) {
      float m_old = m_sh[tid];
      float mn = m_old;
      #pragma unroll
      for (int g = 0; g < 8; ++g) mn = fmaxf(mn, red[tid][g]);
      m_sh[tid] = mn;
      alpha_sh[tid] = __expf(m_old - mn);  // exp(-inf - finite) = 0 on first tile
    }
    __syncthreads();
    const float mn = m_sh[row];
    const float al = alpha_sh[row];
    float psum = 0.f;
    #pragma unroll
    for (int c = 0; c < 4; ++c) {
      float p = __expf(sc[c] - mn);
      Ps[row][jl0 + c] = p;
      psum += p;
    }
    red[row][cg] = psum;
    #pragma unroll
    for (int i = 0; i < 16; ++i) O[i] *= al;
    __syncthreads();   // Ps + red complete
    if (tid < BM) {
      float acc = 0.f;
      #pragma unroll
      for (int g = 0; g < 8; ++g) acc += red[tid][g];
      l_sh[tid] = l_sh[tid] * alpha_sh[tid] + acc;
    }
    // P @ V
    for (int j = 0; j < BN; ++j) {
      float p = Ps[row][j];
      #pragma unroll
      for (int i = 0; i < 16; ++i) O[i] += p * Vs[j][d0 + i];
    }
  }
  __syncthreads();
  const float inv_l = 1.f / l_sh[row];
  float* orow = &o[(size_t)(b * TSEQ + m0 + row) * CDIM + h * DH + d0];
  #pragma unroll
  for (int i = 0; i < 16; ++i) orow[i] = O[i] * inv_l;
}

// ---------------- launch ----------------
extern "C" void kernel_launch(void* const* d_in, const int* in_sizes, int n_in,
                              void* d_out, int out_size, void* d_ws, size_t ws_size,
                              hipStream_t stream) {
  const float* x    = (const float*)d_in[0];
  const float* wq   = (const float*)d_in[1];
  const float* wk   = (const float*)d_in[2];
  const float* wv   = (const float*)d_in[3];
  const float* wo   = (const float*)d_in[4];
  const float* cosb = (const float*)d_in[5];
  const float* sinb = (const float*)d_in[6];
  const int* causal = (const int*)d_in[7];

  // q reuses d_out (overwritten by the final GEMM). ws: k | v | o  = 96 MB.
  float* qbuf = (float*)d_out;
  float* kbuf = (float*)d_ws;
  float* vbuf = kbuf + (size_t)BT * (NKV * DH);
  float* obuf = vbuf + (size_t)BT * (NKV * DH);

  dim3 blk(256);
  // q = rope(x @ wq), k = rope(x @ wk), v = x @ wv
  gemm_rope<<<dim3(CDIM / BLK, BT / BLK), blk, 0, stream>>>(x, wq, qbuf, CDIM, CDIM, cosb, sinb, 1);
  gemm_rope<<<dim3((NKV * DH) / BLK, BT / BLK), blk, 0, stream>>>(x, wk, kbuf, NKV * DH, CDIM, cosb, sinb, 1);
  gemm_rope<<<dim3((NKV * DH) / BLK, BT / BLK), blk, 0, stream>>>(x, wv, vbuf, NKV * DH, CDIM, nullptr, nullptr, 0);
  // attention
  flash_kernel<<<dim3(TSEQ / BM, NH, BSZ), blk, 0, stream>>>(qbuf, kbuf, vbuf, obuf, causal);
  // out = o @ wo  (overwrites d_out; q no longer needed)
  gemm_rope<<<dim3(CDIM / BLK, BT / BLK), blk, 0, stream>>>(obuf, wo, (float*)d_out, CDIM, CDIM, nullptr, nullptr, 0);
}

// Round 3
// 3827.405 us; speedup vs baseline: 1.9737x; 1.9737x over previous
//
#include <hip/hip_runtime.h>
#include <hip/hip_bf16.h>

// Problem constants
#define BSZ   2
#define TSEQ  2048
#define CDIM  4096
#define NH    32
#define NKV   8
#define GQ    4
#define DH    128
#define BT    (BSZ * TSEQ)   // 4096

typedef short   bf16x8  __attribute__((ext_vector_type(8)));
typedef float   f32x4   __attribute__((ext_vector_type(4)));
typedef unsigned short ushort8v __attribute__((ext_vector_type(8)));

#define LDS_AS(p) ((__attribute__((address_space(3))) void*)(p))
#define GLB_AS(p) ((const __attribute__((address_space(1))) void*)(p))

static __device__ inline unsigned short bf16_bits(float f) {
  __hip_bfloat16 h = __float2bfloat16(f);
  return *(unsigned short*)&h;
}
static __device__ inline float bits_f32(unsigned short u) {
  unsigned v = ((unsigned)u) << 16;
  return __builtin_bit_cast(float, v);
}

// ---------------- fp32 -> bf16 elementwise ----------------
__global__ __launch_bounds__(256) void cvt_bf16x4(
    const float* __restrict__ src, __hip_bfloat16* __restrict__ dst, int n4) {
  int i = blockIdx.x * 256 + threadIdx.x;
  if (i >= n4) return;
  float4 v = ((const float4*)src)[i];
  ushort4 o;
  o.x = bf16_bits(v.x); o.y = bf16_bits(v.y);
  o.z = bf16_bits(v.z); o.w = bf16_bits(v.w);
  ((ushort4*)dst)[i] = o;
}

// ---------------- transpose + convert: src K x N fp32 -> dst N x K bf16 ----------------
__global__ __launch_bounds__(256) void transpose_cvt(
    const float* __restrict__ src, __hip_bfloat16* __restrict__ dst, int K, int N) {
  __shared__ float T[64][65];
  const int bn = blockIdx.x * 64;
  const int bk = blockIdx.y * 64;
  const int tid = threadIdx.x;
  for (int i = tid; i < 64 * 16; i += 256) {
    int r = i >> 4, c4 = i & 15;
    float4 v = *(const float4*)&src[(size_t)(bk + r) * N + bn + c4 * 4];
    T[r][c4*4+0] = v.x; T[r][c4*4+1] = v.y; T[r][c4*4+2] = v.z; T[r][c4*4+3] = v.w;
  }
  __syncthreads();
  for (int i = tid; i < 64 * 16; i += 256) {
    int n = i >> 4, k4 = i & 15;
    ushort4 o;
    o.x = bf16_bits(T[k4*4+0][n]); o.y = bf16_bits(T[k4*4+1][n]);
    o.z = bf16_bits(T[k4*4+2][n]); o.w = bf16_bits(T[k4*4+3][n]);
    *(ushort4*)&dst[(size_t)(bn + n) * K + bk + k4 * 4] = o;
  }
}

// ---------------- bf16 MFMA GEMM (m97 structure) ----------------
// C[M x N] = A[M x K bf16 row-major] @ Bt[N x K bf16 row-major]^T
// 128x128 tile, BK=32, 256 threads (4 waves, 2x2), 16x16x32 MFMA, 4x4 acc/wave.
__global__ __launch_bounds__(256) void gemm_mfma(
    const __hip_bfloat16* __restrict__ A, const __hip_bfloat16* __restrict__ Bt,
    void* __restrict__ C, int N, int K, int outBf16) {
  __shared__ __hip_bfloat16 As[128 * 32];   // [row][k], 64 B rows — no padding (global_load_lds)
  __shared__ __hip_bfloat16 Bs[128 * 32];
  const int tid  = threadIdx.x;
  const int lane = tid & 63;
  const int wv   = tid >> 6;
  const int row0 = blockIdx.y * 128;
  const int col0 = blockIdx.x * 128;
  const int wm   = (wv & 1) * 64;
  const int wn   = (wv >> 1) * 64;
  const int lrow = lane & 15;    // m (A) / n (B) within 16x16
  const int kgrp = lane >> 4;    // k quad

  f32x4 zero = {0.f, 0.f, 0.f, 0.f};
  f32x4 acc[4][4];
  #pragma unroll
  for (int mi = 0; mi < 4; ++mi)
    #pragma unroll
    for (int ni = 0; ni < 4; ++ni) acc[mi][ni] = zero;

  for (int k0 = 0; k0 < K; k0 += 32) {
    #pragma unroll
    for (int r = 0; r < 2; ++r) {
      int idx16 = r * 256 + tid;          // 16B chunk index
      int arow  = idx16 >> 2;             // tile row
      int akk   = (idx16 & 3) << 3;       // k element offset
      const __hip_bfloat16* ga = &A [(size_t)(row0 + arow) * K + k0 + akk];
      const __hip_bfloat16* gb = &Bt[(size_t)(col0 + arow) * K + k0 + akk];
      char* la = (char*)As + (r * 4096 + wv * 1024 + lane * 16);
      char* lb = (char*)Bs + (r * 4096 + wv * 1024 + lane * 16);
      __builtin_amdgcn_global_load_lds(GLB_AS(ga), LDS_AS(la), 16, 0, 0);
      __builtin_amdgcn_global_load_lds(GLB_AS(gb), LDS_AS(lb), 16, 0, 0);
    }
    __syncthreads();   // drains vmcnt before barrier
    bf16x8 af[4], bfr[4];
    #pragma unroll
    for (int i = 0; i < 4; ++i) {
      af[i]  = *(const bf16x8*)&As[(wm + i * 16 + lrow) * 32 + kgrp * 8];
      bfr[i] = *(const bf16x8*)&Bs[(wn + i * 16 + lrow) * 32 + kgrp * 8];
    }
    #pragma unroll
    for (int mi = 0; mi < 4; ++mi)
      #pragma unroll
      for (int ni = 0; ni < 4; ++ni)
        acc[mi][ni] = __builtin_amdgcn_mfma_f32_16x16x32_bf16(af[mi], bfr[ni], acc[mi][ni], 0, 0, 0);
    __syncthreads();
  }

  // C/D layout: col = lane&15, row = (lane>>4)*4 + reg  [m89-verified]
  if (outBf16) {
    __hip_bfloat16* Cb = (__hip_bfloat16*)C;
    #pragma unroll
    for (int mi = 0; mi < 4; ++mi)
      #pragma unroll
      for (int ni = 0; ni < 4; ++ni) {
        int col = col0 + wn + ni * 16 + lrow;
        int rowb = row0 + wm + mi * 16 + kgrp * 4;
        #pragma unroll
        for (int r = 0; r < 4; ++r)
          Cb[(size_t)(rowb + r) * N + col] = __float2bfloat16(acc[mi][ni][r]);
      }
  } else {
    float* Cf = (float*)C;
    #pragma unroll
    for (int mi = 0; mi < 4; ++mi)
      #pragma unroll
      for (int ni = 0; ni < 4; ++ni) {
        int col = col0 + wn + ni * 16 + lrow;
        int rowb = row0 + wm + mi * 16 + kgrp * 4;
        #pragma unroll
        for (int r = 0; r < 4; ++r)
          Cf[(size_t)(rowb + r) * N + col] = acc[mi][ni][r];
      }
  }
}

// ---------------- RoPE on a bf16 buffer (interleaved pairs within each 128-wide head) ----------------
__global__ __launch_bounds__(256) void rope_bf16(
    __hip_bfloat16* __restrict__ buf, int stride, int perRow /* width/8 */,
    const float* __restrict__ cosb, const float* __restrict__ sinb) {
  int idx = blockIdx.x * 256 + threadIdx.x;
  int row = idx / perRow;
  if (row >= BT) return;
  int c8 = (idx - row * perRow) * 8;
  int t  = row & (TSEQ - 1);
  int cp = c8 & (DH - 1);
  __hip_bfloat16* p = buf + (size_t)row * stride + c8;
  ushort8v raw = *(const ushort8v*)p;
  const float* cr = &cosb[(size_t)t * DH + cp];
  const float* sr = &sinb[(size_t)t * DH + cp];
  ushort8v outp;
  #pragma unroll
  for (int j = 0; j < 8; j += 2) {
    float x1 = bits_f32(raw[j]), x2 = bits_f32(raw[j + 1]);
    float c = cr[j], s = sr[j];    // cos/sin stored repeated x2 -> value at even idx valid for pair
    outp[j]     = bf16_bits(x1 * c - x2 * s);
    outp[j + 1] = bf16_bits(x1 * s + x2 * c);
  }
  *(ushort8v*)p = outp;
}

// ---------------- flash attention (fp32 math, bf16 I/O) ----------------
#define BM 32
#define BN 32
#define KVLD 2048   // row stride of fused kv buffer

__global__ __launch_bounds__(256) void flash_kernel(
    const __hip_bfloat16* __restrict__ q,   // (BT, 4096) bf16
    const __hip_bfloat16* __restrict__ k,   // (BT, KVLD) col kvh*128+d
    const __hip_bfloat16* __restrict__ v,   // k + 1024
    __hip_bfloat16* __restrict__ o,         // (BT, 4096) bf16
    const int* __restrict__ causal_p) {
  __shared__ float Qs[DH][BM + 1];
  __shared__ float Ks[DH][BN + 1];
  __shared__ float Vs[BN][DH];
  __shared__ float Ps[BM][BN + 1];
  __shared__ float red[BM][8];
  __shared__ float m_sh[BM], l_sh[BM], alpha_sh[BM];

  const int tid = threadIdx.x;
  const int row = tid & 31;
  const int cg  = tid >> 5;
  const int mtile = blockIdx.x;
  const int h  = blockIdx.y;
  const int b  = blockIdx.z;
  const int kvh = h / GQ;
  const int m0 = mtile * BM;
  const bool causal = (*causal_p != 0);
  const float NEG_INF = -__builtin_inff();

  // Q tile transposed, bf16 -> fp32
  for (int idx = tid; idx < BM * (DH / 8); idx += 256) {
    int r  = idx >> 4;
    int c8 = (idx & 15) * 8;
    ushort8v raw = *(const ushort8v*)&q[(size_t)(b * TSEQ + m0 + r) * CDIM + h * DH + c8];
    #pragma unroll
    for (int j = 0; j < 8; ++j) Qs[c8 + j][r] = bits_f32(raw[j]);
  }
  if (tid < BM) { m_sh[tid] = NEG_INF; l_sh[tid] = 0.f; }

  float O[16];
  #pragma unroll
  for (int i = 0; i < 16; ++i) O[i] = 0.f;

  const int ntiles = causal ? (mtile + 1) : (TSEQ / BN);
  const float scale = 0.08838834764831845f;
  const int jl0 = cg * 4;
  const int d0  = cg * 16;

  for (int tile = 0; tile < ntiles; ++tile) {
    const int j0 = tile * BN;
    __syncthreads();
    for (int idx = tid; idx < BN * (DH / 8); idx += 256) {
      int r  = idx >> 4;
      int c8 = (idx & 15) * 8;
      size_t goff = (size_t)(b * TSEQ + j0 + r) * KVLD + kvh * DH + c8;
      ushort8v rk = *(const ushort8v*)&k[goff];
      ushort8v rv = *(const ushort8v*)&v[goff];
      #pragma unroll
      for (int j = 0; j < 8; ++j) {
        Ks[c8 + j][r] = bits_f32(rk[j]);
        Vs[r][c8 + j] = bits_f32(rv[j]);
      }
    }
    __syncthreads();

    float s0 = 0.f, s1 = 0.f, s2 = 0.f, s3 = 0.f;
    #pragma unroll 4
    for (int d = 0; d < DH; ++d) {
      float qv = Qs[d][row];
      s0 += qv * Ks[d][jl0 + 0];
      s1 += qv * Ks[d][jl0 + 1];
      s2 += qv * Ks[d][jl0 + 2];
      s3 += qv * Ks[d][jl0 + 3];
    }
    float sc[4] = {s0 * scale, s1 * scale, s2 * scale, s3 * scale};
    const int t_glob = m0 + row;
    if (causal) {
      #pragma unroll
      for (int c = 0; c < 4; ++c)
        if (j0 + jl0 + c > t_glob) sc[c] = NEG_INF;
    }
    float pmax = fmaxf(fmaxf(sc[0], sc[1]), fmaxf(sc[2], sc[3]));
    red[row][cg] = pmax;
    __syncthreads();
    if (tid < BM) {
      float m_old = m_sh[tid];
      float mn = m_old;
      #pragma unroll
      for (int g = 0; g < 8; ++g) mn = fmaxf(mn, red[tid][g]);
      m_sh[tid] = mn;
      alpha_sh[tid] = __expf(m_old - mn);
    }
    __syncthreads();
    const float mn = m_sh[row];
    const float al = alpha_sh[row];
    float psum = 0.f;
    #pragma unroll
    for (int c = 0; c < 4; ++c) {
      float p = __expf(sc[c] - mn);
      Ps[row][jl0 + c] = p;
      psum += p;
    }
    red[row][cg] = psum;
    #pragma unroll
    for (int i = 0; i < 16; ++i) O[i] *= al;
    __syncthreads();
    if (tid < BM) {
      float acc = 0.f;
      #pragma unroll
      for (int g = 0; g < 8; ++g) acc += red[tid][g];
      l_sh[tid] = l_sh[tid] * alpha_sh[tid] + acc;
    }
    for (int j = 0; j < BN; ++j) {
      float p = Ps[row][j];
      #pragma unroll
      for (int i = 0; i < 16; ++i) O[i] += p * Vs[j][d0 + i];
    }
  }
  __syncthreads();
  const float inv_l = 1.f / l_sh[row];
  __hip_bfloat16* orow = &o[(size_t)(b * TSEQ + m0 + row) * CDIM + h * DH + d0];
  #pragma unroll
  for (int i = 0; i < 16; ++i) orow[i] = __float2bfloat16(O[i] * inv_l);
}

// ---------------- launch ----------------
extern "C" void kernel_launch(void* const* d_in, const int* in_sizes, int n_in,
                              void* d_out, int out_size, void* d_ws, size_t ws_size,
                              hipStream_t stream) {
  const float* x    = (const float*)d_in[0];
  const float* wq   = (const float*)d_in[1];
  const float* wk   = (const float*)d_in[2];
  const float* wv   = (const float*)d_in[3];
  const float* wo   = (const float*)d_in[4];
  const float* cosb = (const float*)d_in[5];
  const float* sinb = (const float*)d_in[6];
  const int* causal = (const int*)d_in[7];

  // ws layout (96 MB peak, time-aliased):
  //  [0,32MB):    xb (bf16 x)          -> later woT
  //  [32,64MB):   wqT                  -> later obuf (bf16 attn out)
  //  [64,80MB):   wkvT (2048 x 4096)
  //  [80,96MB):   kvb  (BT x 2048 bf16; k cols 0..1023, v cols 1024..2047)
  char* wsb = (char*)d_ws;
  __hip_bfloat16* xb   = (__hip_bfloat16*)(wsb);
  __hip_bfloat16* woT  = (__hip_bfloat16*)(wsb);                          // alias xb
  __hip_bfloat16* wqT  = (__hip_bfloat16*)(wsb + (((size_t)32) << 20));
  __hip_bfloat16* obuf = (__hip_bfloat16*)(wsb + (((size_t)32) << 20));   // alias wqT
  __hip_bfloat16* wkvT = (__hip_bfloat16*)(wsb + (((size_t)64) << 20));
  __hip_bfloat16* kvb  = (__hip_bfloat16*)(wsb + (((size_t)80) << 20));
  __hip_bfloat16* qb   = (__hip_bfloat16*)d_out;                          // q bf16 lives in d_out until final GEMM

  dim3 blk(256);
  // 1. x -> bf16
  cvt_bf16x4<<<dim3((BT * CDIM / 4 + 255) / 256), blk, 0, stream>>>(x, xb, BT * CDIM / 4);
  // 2. weights -> transposed bf16
  transpose_cvt<<<dim3(CDIM / 64, CDIM / 64), blk, 0, stream>>>(wq, wqT, CDIM, CDIM);
  transpose_cvt<<<dim3(1024 / 64, CDIM / 64), blk, 0, stream>>>(wk, wkvT, CDIM, 1024);
  transpose_cvt<<<dim3(1024 / 64, CDIM / 64), blk, 0, stream>>>(wv, wkvT + (size_t)1024 * CDIM, CDIM, 1024);
  // 3. q = x @ wq (bf16 out, into d_out)
  gemm_mfma<<<dim3(CDIM / 128, BT / 128), blk, 0, stream>>>(xb, wqT, qb, CDIM, CDIM, 1);
  // 4. kv = x @ [wk|wv] (fused N=2048)
  gemm_mfma<<<dim3(2048 / 128, BT / 128), blk, 0, stream>>>(xb, wkvT, kvb, 2048, CDIM, 1);
  // 5. RoPE on q and k
  rope_bf16<<<dim3(BT * (CDIM / 8) / 256), blk, 0, stream>>>(qb, CDIM, CDIM / 8, cosb, sinb);
  rope_bf16<<<dim3(BT * (1024 / 8) / 256), blk, 0, stream>>>(kvb, 2048, 1024 / 8, cosb, sinb);
  // 6. wo -> woT (overwrites xb; xb last used in step 4)
  transpose_cvt<<<dim3(CDIM / 64, CDIM / 64), blk, 0, stream>>>(wo, woT, CDIM, CDIM);
  // 7. attention (obuf overwrites wqT; wqT last used in step 3)
  flash_kernel<<<dim3(TSEQ / BM, NH, BSZ), blk, 0, stream>>>(qb, kvb, kvb + 1024, obuf, causal);
  // 8. out = o @ wo (fp32 out into d_out; q dead)
  gemm_mfma<<<dim3(CDIM / 128, BT / 128), blk, 0, stream>>>(obuf, woT, d_out, CDIM, CDIM, 0);
}

// Round 4
// 1265.010 us; speedup vs baseline: 5.9716x; 3.0256x over previous
//
#include <hip/hip_runtime.h>
#include <hip/hip_bf16.h>

// Problem constants
#define BSZ   2
#define TSEQ  2048
#define CDIM  4096
#define NH    32
#define NKV   8
#define GQ    4
#define DH    128
#define BT    (BSZ * TSEQ)   // 4096

typedef short   bf16x8  __attribute__((ext_vector_type(8)));
typedef float   f32x4   __attribute__((ext_vector_type(4)));
typedef unsigned short ushort8v __attribute__((ext_vector_type(8)));
typedef unsigned short u16;

#define LDS_AS(p) ((__attribute__((address_space(3))) void*)(p))
#define GLB_AS(p) ((const __attribute__((address_space(1))) void*)(p))

static __device__ inline unsigned short bf16_bits(float f) {
  __hip_bfloat16 h = __float2bfloat16(f);
  return *(unsigned short*)&h;
}
static __device__ inline float bits_f32(unsigned short u) {
  unsigned v = ((unsigned)u) << 16;
  return __builtin_bit_cast(float, v);
}

// ---------------- fp32 -> bf16 elementwise ----------------
__global__ __launch_bounds__(256) void cvt_bf16x4(
    const float* __restrict__ src, __hip_bfloat16* __restrict__ dst, int n4) {
  int i = blockIdx.x * 256 + threadIdx.x;
  if (i >= n4) return;
  float4 v = ((const float4*)src)[i];
  ushort4 o;
  o.x = bf16_bits(v.x); o.y = bf16_bits(v.y);
  o.z = bf16_bits(v.z); o.w = bf16_bits(v.w);
  ((ushort4*)dst)[i] = o;
}

// ---------------- transpose + convert: src K x N fp32 -> dst N x K bf16 ----------------
__global__ __launch_bounds__(256) void transpose_cvt(
    const float* __restrict__ src, __hip_bfloat16* __restrict__ dst, int K, int N) {
  __shared__ float T[64][65];
  const int bn = blockIdx.x * 64;
  const int bk = blockIdx.y * 64;
  const int tid = threadIdx.x;
  for (int i = tid; i < 64 * 16; i += 256) {
    int r = i >> 4, c4 = i & 15;
    float4 v = *(const float4*)&src[(size_t)(bk + r) * N + bn + c4 * 4];
    T[r][c4*4+0] = v.x; T[r][c4*4+1] = v.y; T[r][c4*4+2] = v.z; T[r][c4*4+3] = v.w;
  }
  __syncthreads();
  for (int i = tid; i < 64 * 16; i += 256) {
    int n = i >> 4, k4 = i & 15;
    ushort4 o;
    o.x = bf16_bits(T[k4*4+0][n]); o.y = bf16_bits(T[k4*4+1][n]);
    o.z = bf16_bits(T[k4*4+2][n]); o.w = bf16_bits(T[k4*4+3][n]);
    *(ushort4*)&dst[(size_t)(bn + n) * K + bk + k4 * 4] = o;
  }
}

// ---------------- bf16 MFMA GEMM (m97 structure) ----------------
__global__ __launch_bounds__(256) void gemm_mfma(
    const __hip_bfloat16* __restrict__ A, const __hip_bfloat16* __restrict__ Bt,
    void* __restrict__ C, int N, int K, int outBf16) {
  __shared__ __hip_bfloat16 As[128 * 32];
  __shared__ __hip_bfloat16 Bs[128 * 32];
  const int tid  = threadIdx.x;
  const int lane = tid & 63;
  const int wv   = tid >> 6;
  const int row0 = blockIdx.y * 128;
  const int col0 = blockIdx.x * 128;
  const int wm   = (wv & 1) * 64;
  const int wn   = (wv >> 1) * 64;
  const int lrow = lane & 15;
  const int kgrp = lane >> 4;

  f32x4 zero = {0.f, 0.f, 0.f, 0.f};
  f32x4 acc[4][4];
  #pragma unroll
  for (int mi = 0; mi < 4; ++mi)
    #pragma unroll
    for (int ni = 0; ni < 4; ++ni) acc[mi][ni] = zero;

  for (int k0 = 0; k0 < K; k0 += 32) {
    #pragma unroll
    for (int r = 0; r < 2; ++r) {
      int idx16 = r * 256 + tid;
      int arow  = idx16 >> 2;
      int akk   = (idx16 & 3) << 3;
      const __hip_bfloat16* ga = &A [(size_t)(row0 + arow) * K + k0 + akk];
      const __hip_bfloat16* gb = &Bt[(size_t)(col0 + arow) * K + k0 + akk];
      char* la = (char*)As + (r * 4096 + wv * 1024 + lane * 16);
      char* lb = (char*)Bs + (r * 4096 + wv * 1024 + lane * 16);
      __builtin_amdgcn_global_load_lds(GLB_AS(ga), LDS_AS(la), 16, 0, 0);
      __builtin_amdgcn_global_load_lds(GLB_AS(gb), LDS_AS(lb), 16, 0, 0);
    }
    __syncthreads();
    bf16x8 af[4], bfr[4];
    #pragma unroll
    for (int i = 0; i < 4; ++i) {
      af[i]  = *(const bf16x8*)&As[(wm + i * 16 + lrow) * 32 + kgrp * 8];
      bfr[i] = *(const bf16x8*)&Bs[(wn + i * 16 + lrow) * 32 + kgrp * 8];
    }
    #pragma unroll
    for (int mi = 0; mi < 4; ++mi)
      #pragma unroll
      for (int ni = 0; ni < 4; ++ni)
        acc[mi][ni] = __builtin_amdgcn_mfma_f32_16x16x32_bf16(af[mi], bfr[ni], acc[mi][ni], 0, 0, 0);
    __syncthreads();
  }

  if (outBf16) {
    __hip_bfloat16* Cb = (__hip_bfloat16*)C;
    #pragma unroll
    for (int mi = 0; mi < 4; ++mi)
      #pragma unroll
      for (int ni = 0; ni < 4; ++ni) {
        int col = col0 + wn + ni * 16 + lrow;
        int rowb = row0 + wm + mi * 16 + kgrp * 4;
        #pragma unroll
        for (int r = 0; r < 4; ++r)
          Cb[(size_t)(rowb + r) * N + col] = __float2bfloat16(acc[mi][ni][r]);
      }
  } else {
    float* Cf = (float*)C;
    #pragma unroll
    for (int mi = 0; mi < 4; ++mi)
      #pragma unroll
      for (int ni = 0; ni < 4; ++ni) {
        int col = col0 + wn + ni * 16 + lrow;
        int rowb = row0 + wm + mi * 16 + kgrp * 4;
        #pragma unroll
        for (int r = 0; r < 4; ++r)
          Cf[(size_t)(rowb + r) * N + col] = acc[mi][ni][r];
      }
  }
}

// ---------------- RoPE on a bf16 buffer ----------------
__global__ __launch_bounds__(256) void rope_bf16(
    __hip_bfloat16* __restrict__ buf, int stride, int perRow,
    const float* __restrict__ cosb, const float* __restrict__ sinb) {
  int idx = blockIdx.x * 256 + threadIdx.x;
  int row = idx / perRow;
  if (row >= BT) return;
  int c8 = (idx - row * perRow) * 8;
  int t  = row & (TSEQ - 1);
  int cp = c8 & (DH - 1);
  __hip_bfloat16* p = buf + (size_t)row * stride + c8;
  ushort8v raw = *(const ushort8v*)p;
  const float* cr = &cosb[(size_t)t * DH + cp];
  const float* sr = &sinb[(size_t)t * DH + cp];
  ushort8v outp;
  #pragma unroll
  for (int j = 0; j < 8; j += 2) {
    float x1 = bits_f32(raw[j]), x2 = bits_f32(raw[j + 1]);
    float c = cr[j], s = sr[j];
    outp[j]     = bf16_bits(x1 * c - x2 * s);
    outp[j + 1] = bf16_bits(x1 * s + x2 * c);
  }
  *(ushort8v*)p = outp;
}

// ---------------- V transpose into dense per-(b,kvh,tile) 128x64 blobs ----------------
// src: kvb rows (BT, 2048), v at cols 1024..2047.  dst blob[(b*NKV+kvh)*32+tile][d][t]
__global__ __launch_bounds__(256) void transpose_v(
    const __hip_bfloat16* __restrict__ kvsrc, u16* __restrict__ vt) {
  __shared__ u16 T[64][72];
  const int tid  = threadIdx.x;
  const int tile = blockIdx.x, kvh = blockIdx.y, b = blockIdx.z;
  u16* dst = vt + ((size_t)((b * NKV + kvh) * 32 + tile)) * (128 * 64);
  for (int half = 0; half < 2; ++half) {
    #pragma unroll
    for (int it = 0; it < 2; ++it) {
      int idx = it * 256 + tid;          // 512 chunks = 64 t x 8 d-chunks
      int r = idx >> 3, c8 = idx & 7;
      ushort8v vdat = *(const ushort8v*)&kvsrc[
          (size_t)(b * TSEQ + tile * 64 + r) * 2048 + 1024 + kvh * DH + half * 64 + c8 * 8];
      *(ushort8v*)&T[r][c8 * 8] = vdat;
    }
    __syncthreads();
    #pragma unroll
    for (int it = 0; it < 2; ++it) {
      int idx = it * 256 + tid;
      int d = idx >> 3, c8 = idx & 7;    // d row of output, c8: t-chunk
      ushort8v o8;
      #pragma unroll
      for (int j = 0; j < 8; ++j) o8[j] = T[c8 * 8 + j][d];
      *(ushort8v*)&dst[(size_t)(half * 64 + d) * 64 + c8 * 8] = o8;
    }
    __syncthreads();
  }
}

// ---------------- MFMA flash attention ----------------
// grid (TSEQ/64, NH, BSZ), 256 threads = 4 waves; wave wq handles q rows [m0+wq*16, +16)
#define KSTR 130   // Ks row stride (u16): dw 65 == 1 mod 32 -> conflict-free staging
#define VSTR 66    // Vs row stride
#define PSTR 68    // Ps row stride

__global__ __launch_bounds__(256) void flash_mfma(
    const __hip_bfloat16* __restrict__ q,    // (BT, 4096)
    const __hip_bfloat16* __restrict__ kv,   // kvb (BT, 2048); k at col kvh*128
    const u16* __restrict__ vt,              // V^T blobs
    __hip_bfloat16* __restrict__ o,          // (BT, 4096)
    const int* __restrict__ causal_p) {
  __shared__ u16 Ks[64 * KSTR];     // [kv][d]
  __shared__ u16 Vs[128 * VSTR];    // [d][kv]
  __shared__ u16 Ps[4][16 * PSTR];  // per-wave [q][kv]

  const int tid  = threadIdx.x;
  const int lane = tid & 63;
  const int wq   = tid >> 6;
  const int quad = lane >> 4;
  const int l15  = lane & 15;
  const int mtile = blockIdx.x, h = blockIdx.y, b = blockIdx.z;
  const int kvh = h >> 2;
  const int m0  = mtile * 64;
  const bool causal = (*causal_p != 0);
  const float NEG_INF = -__builtin_inff();
  const float scale = 0.08838834764831845f;

  // Q fragments (loop-invariant): A[m=l15][k=quad*8+j] per 32-wide k chunk
  bf16x8 qf[4];
  {
    const __hip_bfloat16* qrow =
        &q[(size_t)(b * TSEQ + m0 + wq * 16 + l15) * CDIM + h * DH + quad * 8];
    #pragma unroll
    for (int kc = 0; kc < 4; ++kc) qf[kc] = *(const bf16x8*)(qrow + kc * 32);
  }

  f32x4 Ot[8];
  #pragma unroll
  for (int dt = 0; dt < 8; ++dt) Ot[dt] = (f32x4){0.f, 0.f, 0.f, 0.f};
  float mrow[4] = {NEG_INF, NEG_INF, NEG_INF, NEG_INF};
  float lrow[4] = {0.f, 0.f, 0.f, 0.f};

  const int ntiles = causal ? (mtile + 1) : (TSEQ / 64);
  u16* Pw = &Ps[wq][0];

  for (int tile = 0; tile < ntiles; ++tile) {
    const int j0 = tile * 64;
    __syncthreads();   // previous iteration readers done
    // stage K tile: coalesced global, conflict-free LDS (bank = r + 4*c8)
    #pragma unroll
    for (int it = 0; it < 4; ++it) {
      int idx = it * 256 + tid;
      int r = idx >> 4, c8 = idx & 15;
      ushort8v kd = *(const ushort8v*)&kv[(size_t)(b * TSEQ + j0 + r) * 2048 + kvh * DH + c8 * 8];
      *(ushort8v*)&Ks[r * KSTR + c8 * 8] = kd;
    }
    // stage V^T tile from dense blob
    const u16* vblob = vt + ((size_t)((b * NKV + kvh) * 32 + tile)) * (128 * 64);
    #pragma unroll
    for (int it = 0; it < 4; ++it) {
      int idx = it * 256 + tid;
      int d = idx >> 3, c8 = idx & 7;
      ushort8v vd = *(const ushort8v*)&vblob[(size_t)d * 64 + c8 * 8];
      *(ushort8v*)&Vs[d * VSTR + c8 * 8] = vd;
    }
    __syncthreads();

    // S = Q K^T : 4 kv 16-tiles x 4 d-chunks
    f32x4 S[4];
    #pragma unroll
    for (int jt = 0; jt < 4; ++jt) {
      f32x4 acc = {0.f, 0.f, 0.f, 0.f};
      #pragma unroll
      for (int kc = 0; kc < 4; ++kc) {
        bf16x8 kf = *(const bf16x8*)&Ks[(jt * 16 + l15) * KSTR + kc * 32 + quad * 8];
        acc = __builtin_amdgcn_mfma_f32_16x16x32_bf16(qf[kc], kf, acc, 0, 0, 0);
      }
      S[jt] = acc;
    }
    #pragma unroll
    for (int jt = 0; jt < 4; ++jt)
      #pragma unroll
      for (int r = 0; r < 4; ++r) S[jt][r] *= scale;
    if (causal && tile == mtile) {
      const int qr0 = m0 + wq * 16 + quad * 4;
      #pragma unroll
      for (int jt = 0; jt < 4; ++jt)
        #pragma unroll
        for (int r = 0; r < 4; ++r)
          if (j0 + jt * 16 + l15 > qr0 + r) S[jt][r] = NEG_INF;
    }

    // online softmax: rows = quad*4+r, cols across 16 lanes of the quad group
    float rmax[4], alpha[4], rsum[4];
    #pragma unroll
    for (int r = 0; r < 4; ++r) {
      float mx = fmaxf(fmaxf(S[0][r], S[1][r]), fmaxf(S[2][r], S[3][r]));
      #pragma unroll
      for (int w = 1; w <= 8; w <<= 1) mx = fmaxf(mx, __shfl_xor(mx, w));
      rmax[r] = mx;
      float mn = fmaxf(mrow[r], mx);
      alpha[r] = __expf(mrow[r] - mn);
      mrow[r] = mn;
      rsum[r] = 0.f;
    }
    #pragma unroll
    for (int jt = 0; jt < 4; ++jt)
      #pragma unroll
      for (int r = 0; r < 4; ++r) {
        float p = __expf(S[jt][r] - mrow[r]);   // masked -> exp(-inf) = 0
        rsum[r] += p;
        Pw[(quad * 4 + r) * PSTR + jt * 16 + l15] = bf16_bits(p);
      }
    #pragma unroll
    for (int r = 0; r < 4; ++r) {
      float s = rsum[r];
      #pragma unroll
      for (int w = 1; w <= 8; w <<= 1) s += __shfl_xor(s, w);
      lrow[r] = lrow[r] * alpha[r] + s;
    }
    // rescale O
    #pragma unroll
    for (int dt = 0; dt < 8; ++dt)
      #pragma unroll
      for (int r = 0; r < 4; ++r) Ot[dt][r] *= alpha[r];

    // O += P V : A = P[m=q][k=kv], B = V[n=d][k=kv]
    #pragma unroll
    for (int kc = 0; kc < 2; ++kc) {
      bf16x8 pf = *(const bf16x8*)&Pw[l15 * PSTR + kc * 32 + quad * 8];
      #pragma unroll
      for (int dt = 0; dt < 8; ++dt) {
        bf16x8 vf = *(const bf16x8*)&Vs[(dt * 16 + l15) * VSTR + kc * 32 + quad * 8];
        Ot[dt] = __builtin_amdgcn_mfma_f32_16x16x32_bf16(pf, vf, Ot[dt], 0, 0, 0);
      }
    }
  }

  // epilogue: normalize and store
  float invl[4];
  #pragma unroll
  for (int r = 0; r < 4; ++r) invl[r] = 1.f / lrow[r];
  #pragma unroll
  for (int dt = 0; dt < 8; ++dt)
    #pragma unroll
    for (int r = 0; r < 4; ++r)
      o[(size_t)(b * TSEQ + m0 + wq * 16 + quad * 4 + r) * CDIM + h * DH + dt * 16 + l15] =
          __float2bfloat16(Ot[dt][r] * invl[r]);
}

// ---------------- launch ----------------
extern "C" void kernel_launch(void* const* d_in, const int* in_sizes, int n_in,
                              void* d_out, int out_size, void* d_ws, size_t ws_size,
                              hipStream_t stream) {
  const float* x    = (const float*)d_in[0];
  const float* wq   = (const float*)d_in[1];
  const float* wk   = (const float*)d_in[2];
  const float* wv   = (const float*)d_in[3];
  const float* wo   = (const float*)d_in[4];
  const float* cosb = (const float*)d_in[5];
  const float* sinb = (const float*)d_in[6];
  const int* causal = (const int*)d_in[7];

  // ws layout (96 MB peak, time-aliased):
  //  [0,32MB):    xb (bf16 x)          -> later woT
  //  [32,64MB):   wqT                  -> later obuf
  //  [64,80MB):   wkvT                 -> later vT blobs (8 MB)
  //  [80,96MB):   kvb (BT x 2048 bf16; k cols 0..1023, v cols 1024..2047)
  char* wsb = (char*)d_ws;
  __hip_bfloat16* xb   = (__hip_bfloat16*)(wsb);
  __hip_bfloat16* woT  = (__hip_bfloat16*)(wsb);
  __hip_bfloat16* wqT  = (__hip_bfloat16*)(wsb + (((size_t)32) << 20));
  __hip_bfloat16* obuf = (__hip_bfloat16*)(wsb + (((size_t)32) << 20));
  __hip_bfloat16* wkvT = (__hip_bfloat16*)(wsb + (((size_t)64) << 20));
  u16*            vtb  = (u16*)           (wsb + (((size_t)64) << 20));
  __hip_bfloat16* kvb  = (__hip_bfloat16*)(wsb + (((size_t)80) << 20));
  __hip_bfloat16* qb   = (__hip_bfloat16*)d_out;

  dim3 blk(256);
  cvt_bf16x4<<<dim3((BT * CDIM / 4 + 255) / 256), blk, 0, stream>>>(x, xb, BT * CDIM / 4);
  transpose_cvt<<<dim3(CDIM / 64, CDIM / 64), blk, 0, stream>>>(wq, wqT, CDIM, CDIM);
  transpose_cvt<<<dim3(1024 / 64, CDIM / 64), blk, 0, stream>>>(wk, wkvT, CDIM, 1024);
  transpose_cvt<<<dim3(1024 / 64, CDIM / 64), blk, 0, stream>>>(wv, wkvT + (size_t)1024 * CDIM, CDIM, 1024);
  gemm_mfma<<<dim3(CDIM / 128, BT / 128), blk, 0, stream>>>(xb, wqT, qb, CDIM, CDIM, 1);
  gemm_mfma<<<dim3(2048 / 128, BT / 128), blk, 0, stream>>>(xb, wkvT, kvb, 2048, CDIM, 1);
  // V^T blobs (overwrites wkvT, dead after kv GEMM)
  transpose_v<<<dim3(32, NKV, BSZ), blk, 0, stream>>>(kvb, vtb);
  rope_bf16<<<dim3(BT * (CDIM / 8) / 256), blk, 0, stream>>>(qb, CDIM, CDIM / 8, cosb, sinb);
  rope_bf16<<<dim3(BT * (1024 / 8) / 256), blk, 0, stream>>>(kvb, 2048, 1024 / 8, cosb, sinb);
  transpose_cvt<<<dim3(CDIM / 64, CDIM / 64), blk, 0, stream>>>(wo, woT, CDIM, CDIM);
  flash_mfma<<<dim3(TSEQ / 64, NH, BSZ), blk, 0, stream>>>(qb, kvb, vtb, obuf, causal);
  gemm_mfma<<<dim3(CDIM / 128, BT / 128), blk, 0, stream>>>(obuf, woT, d_out, CDIM, CDIM, 0);
}